// Round 10
// baseline (185.402 us; speedup 1.0000x reference)
//
#include <hip/hip_runtime.h>
#include <cstdint>
#include <cstddef>

// ---------------- problem constants ----------------
#define B_ 4
#define S_ 4096
#define E_ 512
#define NPOS 16384      // B*S
#define QKVC 1536       // 3*E
#define K_ 512          // contraction dim of both GEMMs

typedef unsigned short u16;
typedef u16    u16x8  __attribute__((ext_vector_type(8)));
typedef u16    u16x4  __attribute__((ext_vector_type(4)));
typedef __bf16 bf16x8 __attribute__((ext_vector_type(8)));
typedef float  f32x4  __attribute__((ext_vector_type(4)));

__device__ __forceinline__ u16 f2bf(float f) {
    unsigned u = __builtin_bit_cast(unsigned, f);
    unsigned r = (u + 0x7fffu + ((u >> 16) & 1u)) >> 16;   // RNE, finite inputs
    return (u16)r;
}
__device__ __forceinline__ float bf2f(u16 u) {
    return __builtin_bit_cast(float, (unsigned)u << 16);
}
__device__ __forceinline__ float rcpf(float x) { return __builtin_amdgcn_rcpf(x); }

// async global->LDS, 16B per lane; lds base wave-uniform, lane deposits at
// base + laneid*16  [guide §5, m97/m104]
__device__ __forceinline__ void async16(const void* g, void* lds) {
    __builtin_amdgcn_global_load_lds(
        (const __attribute__((address_space(1))) unsigned int*)g,
        (__attribute__((address_space(3))) unsigned int*)lds, 16, 0, 0);
}

// ---------------- fp32 -> bf16 conversion (all three tensors + zero-fill, one launch) ----------
#define CVT_N1 (NPOS * E_ / 4)
#define CVT_N2 (QKVC * E_ / 4)
#define CVT_N3 (E_ * E_ / 4)
#define ZN     (4 * B_ * 512 + 64)     // sumq/sumk/sumqi/sumko + sm, in floats
__global__ void cvt_all(const float4* __restrict__ x,  u16x4* __restrict__ xo,
                        const float4* __restrict__ wq, u16x4* __restrict__ wqo,
                        const float4* __restrict__ wo, u16x4* __restrict__ woo,
                        float* __restrict__ zb) {
    int i = blockIdx.x * 256 + threadIdx.x;
    if (i < ZN) zb[i] = 0.f;            // stream-ordered: done before gemm_qkv's atomics
    const float4* in; u16x4* out; int idx;
    if (i < CVT_N1)                { in = x;  out = xo;  idx = i; }
    else if (i < CVT_N1 + CVT_N2)  { in = wq; out = wqo; idx = i - CVT_N1; }
    else                           { in = wo; out = woo; idx = i - CVT_N1 - CVT_N2; }
    float4 v = in[idx];
    u16x4 o;
    o[0] = f2bf(v.x); o[1] = f2bf(v.y); o[2] = f2bf(v.z); o[3] = f2bf(v.w);
    out[idx] = o;
}

// MFMA micro-step: 8x ds_read_b128 + 16 MFMA.   [R4-proven structure]
__device__ __forceinline__ void mfma_step(const u16* AsB, const u16* BsB,
                                          int wm, int wn, int fr, int fkk,
                                          f32x4 (&acc)[4][4]) {
    bf16x8 a[4], b[4];
    #pragma unroll
    for (int i = 0; i < 4; ++i)
        a[i] = *(const bf16x8*)&AsB[(wm + i * 16 + fr) * 32 + fkk];
    #pragma unroll
    for (int j = 0; j < 4; ++j)
        b[j] = *(const bf16x8*)&BsB[(wn + j * 16 + fr) * 32 + fkk];
    __builtin_amdgcn_s_setprio(1);
    #pragma unroll
    for (int i = 0; i < 4; ++i)
        #pragma unroll
        for (int j = 0; j < 4; ++j)
            acc[i][j] = __builtin_amdgcn_mfma_f32_16x16x32_bf16(a[i], b[j], acc[i][j], 0, 0, 0);
    __builtin_amdgcn_s_setprio(0);
}

// 2-deep pipeline, 3-buffer ring, counted vmcnt.  [R4]
#define GEMM_PIPELINE(NT)                                                     \
    {                                                                          \
        STAGE(0, 0);                                                           \
        STAGE(1, 1);                                                           \
        asm volatile("s_waitcnt vmcnt(4)" ::: "memory");                       \
        __builtin_amdgcn_s_barrier();                                          \
        __builtin_amdgcn_sched_barrier(0);                                     \
        int cb = 0, sb = 1;                                                    \
        for (int t = 0; t < (NT) - 2; ++t) {                                   \
            sb = (sb == 2) ? 0 : sb + 1;                                       \
            STAGE(t + 2, sb);                                                  \
            mfma_step(As[cb], Bs[cb], wm, wn, fr, fkk, acc);                   \
            asm volatile("s_waitcnt vmcnt(4)" ::: "memory");                   \
            __builtin_amdgcn_s_barrier();                                      \
            __builtin_amdgcn_sched_barrier(0);                                 \
            cb = (cb == 2) ? 0 : cb + 1;                                       \
        }                                                                      \
        mfma_step(As[cb], Bs[cb], wm, wn, fr, fkk, acc);                       \
        asm volatile("s_waitcnt vmcnt(0)" ::: "memory");                       \
        __builtin_amdgcn_s_barrier();                                          \
        __builtin_amdgcn_sched_barrier(0);                                     \
        cb = (cb == 2) ? 0 : cb + 1;                                           \
        mfma_step(As[cb], Bs[cb], wm, wn, fr, fkk, acc);                       \
    }

// ---------------- GEMM1 (R4 exact): 128^2, XCD-chunked, fused column sums ----------------
__global__ __launch_bounds__(256) void gemm_qkv(
        const u16* __restrict__ A, const u16* __restrict__ Bw,
        const float* __restrict__ bias,
        u16* __restrict__ Qb, u16* __restrict__ Kb, u16* __restrict__ Vb,
        float* __restrict__ sumq, float* __restrict__ sumk,
        int K) {
    __shared__ u16 As[3][128 * 32];
    __shared__ u16 Bs[3][128 * 32];
    const int tid  = threadIdx.x;
    const int wave = tid >> 6, lane = tid & 63;
    const int bid = blockIdx.x;                 // 0..1535
    const int swz = (bid & 7) * 192 + (bid >> 3);
    const int m0 = (swz / 12) * 128, n0 = (swz % 12) * 128;
    const int wm = (wave & 1) * 64, wn = (wave >> 1) * 64;

    const int srow = wave * 16 + (lane >> 2);
    const int cgs  = (lane & 3) ^ ((lane >> 2) & 3) ^ ((lane >> 4) & 3);
    const u16* Ap = A  + (size_t)(m0 + srow) * K + cgs * 8;
    const u16* Bp = Bw + (size_t)(n0 + srow) * K + cgs * 8;
    const int woff = wave * 512;
    const size_t rstep = (size_t)64 * K;

    f32x4 acc[4][4] = {};
    const int fr  = lane & 15;
    const int fkk = (((lane >> 4) ^ (fr & 3) ^ ((fr >> 2) & 3))) * 8;

    #define STAGE(t, buf)                                             \
        async16(Ap + (t) * 32,         &As[buf][woff]);               \
        async16(Ap + (t) * 32 + rstep, &As[buf][woff + 2048]);        \
        async16(Bp + (t) * 32,         &Bs[buf][woff]);               \
        async16(Bp + (t) * 32 + rstep, &Bs[buf][woff + 2048]);

    const int nt = K >> 5;
    GEMM_PIPELINE(nt)
    #undef STAGE

    // epilogue: C/D col = lane&15, row = (lane>>4)*4 + reg   [m89/m91]
    const int cn = lane & 15, rb = (lane >> 4) * 4;
    const int cg2  = (n0 + wn) >> 6;      // wave-uniform 64-col group
    const int type = cg2 % 3;
    const int hb   = cg2 / 3;
    u16* dst = (type == 0) ? Qb : (type == 1) ? Kb : Vb;
    const bool sg = (type < 2);
    float colsum[4] = {};
    #pragma unroll
    for (int i = 0; i < 4; ++i) {
        int mbase = m0 + wm + i * 16 + rb;
        #pragma unroll
        for (int j = 0; j < 4; ++j) {
            int ccol = j * 16 + cn;                     // 0..63 within group
            float bv = bias[n0 + wn + ccol];
            int outcol = hb * 64 + ccol;
            f32x4 av = acc[i][j];
            #pragma unroll
            for (int r = 0; r < 4; ++r) {
                float v = av[r] + bv;
                if (sg) { v = 1.f / (1.f + __expf(-v)); colsum[j] += v; }
                dst[(size_t)(mbase + r) * 512 + outcol] = f2bf(v);
            }
        }
    }
    if (sg) {
        float* sdst = (type == 0) ? sumq : sumk;
        const int b = m0 >> 12;
        #pragma unroll
        for (int j = 0; j < 4; ++j) {
            float s = colsum[j];
            s += __shfl_xor(s, 16);
            s += __shfl_xor(s, 32);
            if (lane < 16)
                atomicAdd(&sdst[b * 512 + hb * 64 + j * 16 + cn], s);
        }
    }
}

// ---------------- GEMM2 (R4 exact): out = r @ Wout^T + b ----------------
__global__ __launch_bounds__(256) void gemm_out(
        const u16* __restrict__ A, const u16* __restrict__ Bw,
        const float* __restrict__ bias, float* __restrict__ C,
        int N, int K) {
    __shared__ u16 As[3][128 * 32];
    __shared__ u16 Bs[3][128 * 32];
    const int tid  = threadIdx.x;
    const int wave = tid >> 6, lane = tid & 63;
    const int bid = blockIdx.x;                 // 0..511
    const int swz = (bid & 7) * 64 + (bid >> 3);
    const int m0 = (swz >> 2) * 128, n0 = (swz & 3) * 128;
    const int wm = (wave & 1) * 64, wn = (wave >> 1) * 64;
    const int srow = wave * 16 + (lane >> 2);
    const int cgs  = (lane & 3) ^ ((lane >> 2) & 3) ^ ((lane >> 4) & 3);
    const u16* Ap = A  + (size_t)(m0 + srow) * K + cgs * 8;
    const u16* Bp = Bw + (size_t)(n0 + srow) * K + cgs * 8;
    const int woff = wave * 512;
    const size_t rstep = (size_t)64 * K;
    f32x4 acc[4][4] = {};
    const int fr  = lane & 15;
    const int fkk = (((lane >> 4) ^ (fr & 3) ^ ((fr >> 2) & 3))) * 8;

    #define STAGE(t, buf)                                             \
        async16(Ap + (t) * 32,         &As[buf][woff]);               \
        async16(Ap + (t) * 32 + rstep, &As[buf][woff + 2048]);        \
        async16(Bp + (t) * 32,         &Bs[buf][woff]);               \
        async16(Bp + (t) * 32 + rstep, &Bs[buf][woff + 2048]);

    const int nt = K >> 5;
    GEMM_PIPELINE(nt)
    #undef STAGE

    const int cn = lane & 15, rb = (lane >> 4) * 4;
    #pragma unroll
    for (int i = 0; i < 4; ++i) {
        int mbase = m0 + wm + i * 16 + rb;
        #pragma unroll
        for (int j = 0; j < 4; ++j) {
            int nn = n0 + wn + j * 16 + cn;
            float bv = bias[nn];
            f32x4 av = acc[i][j];
            #pragma unroll
            for (int r = 0; r < 4; ++r)
                C[(size_t)(mbase + r) * N + nn] = av[r] + bv;
        }
    }
}

// ---------------- fused: i,o dots + partial sums of q/i, k/o ----------------
// grid (4, 256) x 256: 16 positions/block (4/wave) — 2x blocks of R9 for 2x TLP
// (latency-bound: dependent dot -> shfl chain per position).
__global__ __launch_bounds__(256) void fused_io(const u16* __restrict__ Qg, const u16* __restrict__ Kg,
                                                const float* __restrict__ sumq, const float* __restrict__ sumk,
                                                float* __restrict__ iv,
                                                float* __restrict__ sumqi, float* __restrict__ sumko) {
    int b = blockIdx.x, sc = blockIdx.y;
    int w = threadIdx.x >> 6, lane = threadIdx.x & 63;
    float skL[8], sqL[8];
    #pragma unroll
    for (int j = 0; j < 8; ++j) {
        skL[j] = sumk[b * 512 + lane * 8 + j];
        sqL[j] = sumq[b * 512 + lane * 8 + j];
    }
    float aqi[8] = {}, ako[8] = {};
    int p0 = b * S_ + sc * 16 + w * 4;
    for (int it = 0; it < 4; ++it) {
        int p = p0 + it;
        size_t off = (size_t)p * 512 + lane * 8;
        u16x8 q8 = *(const u16x8*)(Qg + off);
        u16x8 k8 = *(const u16x8*)(Kg + off);
        float qf[8], kf[8];
        #pragma unroll
        for (int j = 0; j < 8; ++j) { qf[j] = bf2f(q8[j]); kf[j] = bf2f(k8[j]); }
        float di = 0.f, dox = 0.f;
        #pragma unroll
        for (int j = 0; j < 8; ++j) { di += qf[j] * skL[j]; dox += kf[j] * sqL[j]; }
        di  += __shfl_xor(di, 1);  di  += __shfl_xor(di, 2);  di  += __shfl_xor(di, 4);
        dox += __shfl_xor(dox, 1); dox += __shfl_xor(dox, 2); dox += __shfl_xor(dox, 4);
        if ((lane & 7) == 0) iv[(size_t)p * 8 + (lane >> 3)] = di;
        float ri = rcpf(di), ro = rcpf(dox);
        #pragma unroll
        for (int j = 0; j < 8; ++j) { aqi[j] += qf[j] * ri; ako[j] += kf[j] * ro; }
    }
    __shared__ float red[4][1024];
    #pragma unroll
    for (int j = 0; j < 8; ++j) {
        red[w][lane * 8 + j]       = aqi[j];
        red[w][512 + lane * 8 + j] = ako[j];
    }
    __syncthreads();
    int t = threadIdx.x;
    #pragma unroll
    for (int rr = 0; rr < 4; ++rr) {
        int slot = rr * 256 + t;
        float s = red[0][slot] + red[1][slot] + red[2][slot] + red[3][slot];
        float* dst = (slot < 512) ? &sumqi[b * 512 + slot] : &sumko[b * 512 + (slot - 512)];
        atomicAdd(dst, s);
    }
}

// ---------------- io2: i_hat,o_hat -> rowsc, wexp, sm partials ----------------
// grid (4, 256) x 256: 16 positions/block (4/wave).
__global__ __launch_bounds__(256) void io2_kernel(const u16* __restrict__ Qg, const u16* __restrict__ Kg,
                                                  const float* __restrict__ sumqi, const float* __restrict__ sumko,
                                                  const float* __restrict__ iv,
                                                  float* __restrict__ rowsc, float* __restrict__ wexp,
                                                  float* __restrict__ sm) {
    int b = blockIdx.x, sc = blockIdx.y;
    int w = threadIdx.x >> 6, lane = threadIdx.x & 63;
    float skoL[8], sqiL[8];
    #pragma unroll
    for (int j = 0; j < 8; ++j) {
        skoL[j] = sumko[b * 512 + lane * 8 + j];
        sqiL[j] = sumqi[b * 512 + lane * 8 + j];
    }
    float smacc = 0.f;
    int p0 = b * S_ + sc * 16 + w * 4;
    for (int it = 0; it < 4; ++it) {
        int p = p0 + it;
        size_t off = (size_t)p * 512 + lane * 8;
        u16x8 q8 = *(const u16x8*)(Qg + off);
        u16x8 k8 = *(const u16x8*)(Kg + off);
        float dih = 0.f, doh = 0.f;
        #pragma unroll
        for (int j = 0; j < 8; ++j) {
            dih += bf2f(q8[j]) * skoL[j];
            doh += bf2f(k8[j]) * sqiL[j];
        }
        dih += __shfl_xor(dih, 1); dih += __shfl_xor(dih, 2); dih += __shfl_xor(dih, 4);
        doh += __shfl_xor(doh, 1); doh += __shfl_xor(doh, 2); doh += __shfl_xor(doh, 4);
        if ((lane & 7) == 0) {
            int h = lane >> 3;
            float sig = 1.f / (1.f + __expf(-dih));
            rowsc[(size_t)p * 8 + h] = sig * rcpf(iv[(size_t)p * 8 + h]);
            float we = __expf(fminf(doh, 80.f));   // softmax w/o max-sub: o_hat ~ O(1)
            wexp[(size_t)p * 8 + h] = we;
            smacc += we;
        }
    }
    __shared__ float sr[4][8];
    if ((lane & 7) == 0) sr[w][lane >> 3] = smacc;
    __syncthreads();
    if (threadIdx.x < 8)
        atomicAdd(&sm[b * 8 + threadIdx.x],
                  sr[0][threadIdx.x] + sr[1][threadIdx.x] + sr[2][threadIdx.x] + sr[3][threadIdx.x]);
}

// ---------------- finalize: MFMA QK^T (2 pos/wave) + PV mix -> r bf16  (grid NPOS/8 x 256) ----------------
__global__ __launch_bounds__(256) void finalize_kernel(
        const u16* __restrict__ Qg, const u16* __restrict__ Kg, const u16* __restrict__ Vg,
        const float* __restrict__ rowsc, const float* __restrict__ wexp, const float* __restrict__ sm,
        u16* __restrict__ Rg) {
    __shared__ float Ml[4][2][8][9];
    __shared__ float vw[4][2][8][68];
    int w = threadIdx.x >> 6, lane = threadIdx.x & 63;
    int p0 = (blockIdx.x * 4 + w) * 2;
    int b = p0 >> 12;

    // QK^T via MFMA: A rows m = (p_l, h) from Q, B rows n = (p_l, h2) from K.
    {
        int pl = (lane >> 3) & 1, hh = lane & 7, quad = lane >> 4;
        const u16* qa = Qg + (size_t)(p0 + pl) * 512 + hh * 64 + quad * 8;
        const u16* ka = Kg + (size_t)(p0 + pl) * 512 + hh * 64 + quad * 8;
        bf16x8 a0 = __builtin_bit_cast(bf16x8, *(const u16x8*)qa);
        bf16x8 a1 = __builtin_bit_cast(bf16x8, *(const u16x8*)(qa + 32));
        bf16x8 b0 = __builtin_bit_cast(bf16x8, *(const u16x8*)ka);
        bf16x8 b1 = __builtin_bit_cast(bf16x8, *(const u16x8*)(ka + 32));
        f32x4 accm = {0.f, 0.f, 0.f, 0.f};
        accm = __builtin_amdgcn_mfma_f32_16x16x32_bf16(a0, b0, accm, 0, 0, 0);
        accm = __builtin_amdgcn_mfma_f32_16x16x32_bf16(a1, b1, accm, 0, 0, 0);
        // C: row=(lane>>4)*4+r, col=lane&15.  Keep diagonal p-quadrants.
        if (((lane >> 5) & 1) == ((lane >> 3) & 1)) {
            int plm = lane >> 5, hr = ((lane >> 4) & 1) * 4, h2 = lane & 7;
            #pragma unroll
            for (int r = 0; r < 4; ++r) Ml[w][plm][hr + r][h2] = accm[r];
        }
    }
    // vw = v * softmax-weight, fp32 in LDS
    {
        int hv = lane >> 3, e0 = (lane & 7) * 8;
        float invsm = rcpf(sm[b * 8 + hv]);
        #pragma unroll
        for (int pl = 0; pl < 2; ++pl) {
            u16x8 v8 = *(const u16x8*)(Vg + (size_t)(p0 + pl) * 512 + lane * 8);
            float wgt = wexp[(size_t)(p0 + pl) * 8 + hv] * invsm;
            f32x4 x0, x1;
            #pragma unroll
            for (int j = 0; j < 4; ++j) { x0[j] = bf2f(v8[j]) * wgt; x1[j] = bf2f(v8[4 + j]) * wgt; }
            *(f32x4*)&vw[w][pl][hv][e0]     = x0;
            *(f32x4*)&vw[w][pl][hv][e0 + 4] = x1;
        }
    }
    __syncthreads();   // order intra-wave cross-lane LDS deps safely
    // PV: lane covers (p_l = lane>>5, h = (lane&31)>>2, 16-elem e-chunk)
    {
        int pl = lane >> 5, idx = lane & 31, h = idx >> 2, eq = (idx & 3) * 16;
        float out[16] = {};
        #pragma unroll
        for (int h2 = 0; h2 < 8; ++h2) {
            float m = Ml[w][pl][h][h2];
            #pragma unroll
            for (int c = 0; c < 4; ++c) {
                f32x4 vv = *(const f32x4*)&vw[w][pl][h2][eq + c * 4];
                #pragma unroll
                for (int j = 0; j < 4; ++j) out[c * 4 + j] += m * vv[j];
            }
        }
        float rs = rowsc[(size_t)(p0 + pl) * 8 + h];
        u16x8 o0, o1;
        #pragma unroll
        for (int j = 0; j < 8; ++j) { o0[j] = f2bf(out[j] * rs); o1[j] = f2bf(out[8 + j] * rs); }
        u16* dst = Rg + (size_t)(p0 + pl) * 512 + h * 64 + eq;
        *(u16x8*)dst       = o0;
        *(u16x8*)(dst + 8) = o1;
    }
}

// ---------------- launch ----------------
extern "C" void kernel_launch(void* const* d_in, const int* in_sizes, int n_in,
                              void* d_out, int out_size, void* d_ws, size_t ws_size,
                              hipStream_t stream) {
    const float* x    = (const float*)d_in[0];
    const float* Wqkv = (const float*)d_in[1];
    const float* bqkv = (const float*)d_in[2];
    const float* Wout = (const float*)d_in[3];
    const float* bout = (const float*)d_in[4];
    float* out = (float*)d_out;
    char* ws = (char*)d_ws;

    constexpr size_t SZ_XBF  = (size_t)NPOS * E_ * 2;     // 16 MB (reused for r)
    constexpr size_t SZ_WQBF = (size_t)QKVC * E_ * 2;
    constexpr size_t SZ_WOBF = (size_t)E_ * E_ * 2;
    constexpr size_t SZ_QKVB = (size_t)NPOS * E_ * 2;     // 16 MB each of Q,K,V
    constexpr size_t SZ_SUM  = (size_t)B_ * 512 * 4;      // 8 KB each
    constexpr size_t SZ_V8   = (size_t)NPOS * 8 * 4;      // 512 KB each

    size_t off = 0;
    u16*   xbf   = (u16*)(ws + off);   off += SZ_XBF;
    u16*   wqbf  = (u16*)(ws + off);   off += SZ_WQBF;
    u16*   wobf  = (u16*)(ws + off);   off += SZ_WOBF;
    u16*   Qb    = (u16*)(ws + off);   off += SZ_QKVB;
    u16*   Kb    = (u16*)(ws + off);   off += SZ_QKVB;
    u16*   Vb    = (u16*)(ws + off);   off += SZ_QKVB;
    float* zbase = (float*)(ws + off);             // contiguous zeroed region (ZN floats):
    float* sumq  = (float*)(ws + off); off += SZ_SUM;
    float* sumk  = (float*)(ws + off); off += SZ_SUM;
    float* sumqi = (float*)(ws + off); off += SZ_SUM;
    float* sumko = (float*)(ws + off); off += SZ_SUM;
    float* sm    = (float*)(ws + off); off += 256;
    float* iv    = (float*)(ws + off); off += SZ_V8;
    float* rowsc = (float*)(ws + off); off += SZ_V8;
    float* wexp  = (float*)(ws + off); off += SZ_V8;
    u16*   rbf   = xbf;   // reuse after GEMM1

    cvt_all<<<(CVT_N1 + CVT_N2 + CVT_N3) / 256, 256, 0, stream>>>(
        (const float4*)x, (u16x4*)xbf,
        (const float4*)Wqkv, (u16x4*)wqbf,
        (const float4*)Wout, (u16x4*)wobf,
        zbase);

    gemm_qkv<<<dim3((QKVC / 128) * (NPOS / 128)), 256, 0, stream>>>(xbf, wqbf, bqkv, Qb, Kb, Vb, sumq, sumk, K_);

    fused_io<<<dim3(B_, 256), 256, 0, stream>>>(Qb, Kb, sumq, sumk, iv, sumqi, sumko);
    io2_kernel<<<dim3(B_, 256), 256, 0, stream>>>(Qb, Kb, sumqi, sumko, iv, rowsc, wexp, sm);
    finalize_kernel<<<NPOS / 8, 256, 0, stream>>>(Qb, Kb, Vb, rowsc, wexp, sm, rbf);

    gemm_out<<<dim3((E_ / 128) * (NPOS / 128)), 256, 0, stream>>>(rbf, wobf, bout, out, E_, K_);
}

// Round 11
// 181.944 us; speedup vs baseline: 1.0190x; 1.0190x over previous
//
#include <hip/hip_runtime.h>
#include <cstdint>
#include <cstddef>

// ---------------- problem constants ----------------
#define B_ 4
#define S_ 4096
#define E_ 512
#define NPOS 16384      // B*S
#define QKVC 1536       // 3*E
#define K_ 512          // contraction dim of both GEMMs

typedef unsigned short u16;
typedef u16    u16x8  __attribute__((ext_vector_type(8)));
typedef u16    u16x4  __attribute__((ext_vector_type(4)));
typedef __bf16 bf16x8 __attribute__((ext_vector_type(8)));
typedef float  f32x4  __attribute__((ext_vector_type(4)));

__device__ __forceinline__ u16 f2bf(float f) {
    unsigned u = __builtin_bit_cast(unsigned, f);
    unsigned r = (u + 0x7fffu + ((u >> 16) & 1u)) >> 16;   // RNE, finite inputs
    return (u16)r;
}
__device__ __forceinline__ float bf2f(u16 u) {
    return __builtin_bit_cast(float, (unsigned)u << 16);
}
__device__ __forceinline__ float rcpf(float x) { return __builtin_amdgcn_rcpf(x); }

// async global->LDS, 16B per lane; lds base wave-uniform, lane deposits at
// base + laneid*16  [guide §5, m97/m104]
__device__ __forceinline__ void async16(const void* g, void* lds) {
    __builtin_amdgcn_global_load_lds(
        (const __attribute__((address_space(1))) unsigned int*)g,
        (__attribute__((address_space(3))) unsigned int*)lds, 16, 0, 0);
}

// ---------------- fp32 -> bf16 conversion (all three tensors, one launch) ----------------
#define CVT_N1 (NPOS * E_ / 4)
#define CVT_N2 (QKVC * E_ / 4)
#define CVT_N3 (E_ * E_ / 4)
__global__ void cvt_all(const float4* __restrict__ x,  u16x4* __restrict__ xo,
                        const float4* __restrict__ wq, u16x4* __restrict__ wqo,
                        const float4* __restrict__ wo, u16x4* __restrict__ woo) {
    int i = blockIdx.x * 256 + threadIdx.x;
    const float4* in; u16x4* out; int idx;
    if (i < CVT_N1)                { in = x;  out = xo;  idx = i; }
    else if (i < CVT_N1 + CVT_N2)  { in = wq; out = wqo; idx = i - CVT_N1; }
    else                           { in = wo; out = woo; idx = i - CVT_N1 - CVT_N2; }
    float4 v = in[idx];
    u16x4 o;
    o[0] = f2bf(v.x); o[1] = f2bf(v.y); o[2] = f2bf(v.z); o[3] = f2bf(v.w);
    out[idx] = o;
}

// MFMA micro-step: 8x ds_read_b128 + 16 MFMA.   [R4-proven 52.2 us structure]
__device__ __forceinline__ void mfma_step(const u16* AsB, const u16* BsB,
                                          int wm, int wn, int fr, int fkk,
                                          f32x4 (&acc)[4][4]) {
    bf16x8 a[4], b[4];
    #pragma unroll
    for (int i = 0; i < 4; ++i)
        a[i] = *(const bf16x8*)&AsB[(wm + i * 16 + fr) * 32 + fkk];
    #pragma unroll
    for (int j = 0; j < 4; ++j)
        b[j] = *(const bf16x8*)&BsB[(wn + j * 16 + fr) * 32 + fkk];
    __builtin_amdgcn_s_setprio(1);
    #pragma unroll
    for (int i = 0; i < 4; ++i)
        #pragma unroll
        for (int j = 0; j < 4; ++j)
            acc[i][j] = __builtin_amdgcn_mfma_f32_16x16x32_bf16(a[i], b[j], acc[i][j], 0, 0, 0);
    __builtin_amdgcn_s_setprio(0);
}

// 2-deep pipeline, 3-buffer ring, counted vmcnt.  [R4]
#define GEMM_PIPELINE(NT)                                                     \
    {                                                                          \
        STAGE(0, 0);                                                           \
        STAGE(1, 1);                                                           \
        asm volatile("s_waitcnt vmcnt(4)" ::: "memory");                       \
        __builtin_amdgcn_s_barrier();                                          \
        __builtin_amdgcn_sched_barrier(0);                                     \
        int cb = 0, sb = 1;                                                    \
        for (int t = 0; t < (NT) - 2; ++t) {                                   \
            sb = (sb == 2) ? 0 : sb + 1;                                       \
            STAGE(t + 2, sb);                                                  \
            mfma_step(As[cb], Bs[cb], wm, wn, fr, fkk, acc);                   \
            asm volatile("s_waitcnt vmcnt(4)" ::: "memory");                   \
            __builtin_amdgcn_s_barrier();                                      \
            __builtin_amdgcn_sched_barrier(0);                                 \
            cb = (cb == 2) ? 0 : cb + 1;                                       \
        }                                                                      \
        mfma_step(As[cb], Bs[cb], wm, wn, fr, fkk, acc);                       \
        asm volatile("s_waitcnt vmcnt(0)" ::: "memory");                       \
        __builtin_amdgcn_s_barrier();                                          \
        __builtin_amdgcn_sched_barrier(0);                                     \
        cb = (cb == 2) ? 0 : cb + 1;                                           \
        mfma_step(As[cb], Bs[cb], wm, wn, fr, fkk, acc);                       \
    }

// ---------------- GEMM1 (R4 exact): 128^2, XCD-chunked, fused column sums ----------------
__global__ __launch_bounds__(256) void gemm_qkv(
        const u16* __restrict__ A, const u16* __restrict__ Bw,
        const float* __restrict__ bias,
        u16* __restrict__ Qb, u16* __restrict__ Kb, u16* __restrict__ Vb,
        float* __restrict__ sumq, float* __restrict__ sumk,
        int K) {
    __shared__ u16 As[3][128 * 32];
    __shared__ u16 Bs[3][128 * 32];
    const int tid  = threadIdx.x;
    const int wave = tid >> 6, lane = tid & 63;
    const int bid = blockIdx.x;                 // 0..1535
    const int swz = (bid & 7) * 192 + (bid >> 3);
    const int m0 = (swz / 12) * 128, n0 = (swz % 12) * 128;
    const int wm = (wave & 1) * 64, wn = (wave >> 1) * 64;

    const int srow = wave * 16 + (lane >> 2);
    const int cgs  = (lane & 3) ^ ((lane >> 2) & 3) ^ ((lane >> 4) & 3);
    const u16* Ap = A  + (size_t)(m0 + srow) * K + cgs * 8;
    const u16* Bp = Bw + (size_t)(n0 + srow) * K + cgs * 8;
    const int woff = wave * 512;
    const size_t rstep = (size_t)64 * K;

    f32x4 acc[4][4] = {};
    const int fr  = lane & 15;
    const int fkk = (((lane >> 4) ^ (fr & 3) ^ ((fr >> 2) & 3))) * 8;

    #define STAGE(t, buf)                                             \
        async16(Ap + (t) * 32,         &As[buf][woff]);               \
        async16(Ap + (t) * 32 + rstep, &As[buf][woff + 2048]);        \
        async16(Bp + (t) * 32,         &Bs[buf][woff]);               \
        async16(Bp + (t) * 32 + rstep, &Bs[buf][woff + 2048]);

    const int nt = K >> 5;
    GEMM_PIPELINE(nt)
    #undef STAGE

    // epilogue: C/D col = lane&15, row = (lane>>4)*4 + reg   [m89/m91]
    const int cn = lane & 15, rb = (lane >> 4) * 4;
    const int cg2  = (n0 + wn) >> 6;      // wave-uniform 64-col group
    const int type = cg2 % 3;
    const int hb   = cg2 / 3;
    u16* dst = (type == 0) ? Qb : (type == 1) ? Kb : Vb;
    const bool sg = (type < 2);
    float colsum[4] = {};
    #pragma unroll
    for (int i = 0; i < 4; ++i) {
        int mbase = m0 + wm + i * 16 + rb;
        #pragma unroll
        for (int j = 0; j < 4; ++j) {
            int ccol = j * 16 + cn;                     // 0..63 within group
            float bv = bias[n0 + wn + ccol];
            int outcol = hb * 64 + ccol;
            f32x4 av = acc[i][j];
            #pragma unroll
            for (int r = 0; r < 4; ++r) {
                float v = av[r] + bv;
                if (sg) { v = 1.f / (1.f + __expf(-v)); colsum[j] += v; }
                dst[(size_t)(mbase + r) * 512 + outcol] = f2bf(v);
            }
        }
    }
    if (sg) {
        float* sdst = (type == 0) ? sumq : sumk;
        const int b = m0 >> 12;
        #pragma unroll
        for (int j = 0; j < 4; ++j) {
            float s = colsum[j];
            s += __shfl_xor(s, 16);
            s += __shfl_xor(s, 32);
            if (lane < 16)
                atomicAdd(&sdst[b * 512 + hb * 64 + j * 16 + cn], s);
        }
    }
}

// ---------------- GEMM2 (R4 exact): out = r @ Wout^T + b ----------------
__global__ __launch_bounds__(256) void gemm_out(
        const u16* __restrict__ A, const u16* __restrict__ Bw,
        const float* __restrict__ bias, float* __restrict__ C,
        int N, int K) {
    __shared__ u16 As[3][128 * 32];
    __shared__ u16 Bs[3][128 * 32];
    const int tid  = threadIdx.x;
    const int wave = tid >> 6, lane = tid & 63;
    const int bid = blockIdx.x;                 // 0..511
    const int swz = (bid & 7) * 64 + (bid >> 3);
    const int m0 = (swz >> 2) * 128, n0 = (swz & 3) * 128;
    const int wm = (wave & 1) * 64, wn = (wave >> 1) * 64;
    const int srow = wave * 16 + (lane >> 2);
    const int cgs  = (lane & 3) ^ ((lane >> 2) & 3) ^ ((lane >> 4) & 3);
    const u16* Ap = A  + (size_t)(m0 + srow) * K + cgs * 8;
    const u16* Bp = Bw + (size_t)(n0 + srow) * K + cgs * 8;
    const int woff = wave * 512;
    const size_t rstep = (size_t)64 * K;
    f32x4 acc[4][4] = {};
    const int fr  = lane & 15;
    const int fkk = (((lane >> 4) ^ (fr & 3) ^ ((fr >> 2) & 3))) * 8;

    #define STAGE(t, buf)                                             \
        async16(Ap + (t) * 32,         &As[buf][woff]);               \
        async16(Ap + (t) * 32 + rstep, &As[buf][woff + 2048]);        \
        async16(Bp + (t) * 32,         &Bs[buf][woff]);               \
        async16(Bp + (t) * 32 + rstep, &Bs[buf][woff + 2048]);

    const int nt = K >> 5;
    GEMM_PIPELINE(nt)
    #undef STAGE

    const int cn = lane & 15, rb = (lane >> 4) * 4;
    #pragma unroll
    for (int i = 0; i < 4; ++i) {
        int mbase = m0 + wm + i * 16 + rb;
        #pragma unroll
        for (int j = 0; j < 4; ++j) {
            int nn = n0 + wn + j * 16 + cn;
            float bv = bias[nn];
            f32x4 av = acc[i][j];
            #pragma unroll
            for (int r = 0; r < 4; ++r)
                C[(size_t)(mbase + r) * N + nn] = av[r] + bv;
        }
    }
}

// ---------------- fused: i,o dots + partial sums of q/i, k/o  (grid (4,128) x 256) ----------------
__global__ __launch_bounds__(256) void fused_io(const u16* __restrict__ Qg, const u16* __restrict__ Kg,
                                                const float* __restrict__ sumq, const float* __restrict__ sumk,
                                                float* __restrict__ iv,
                                                float* __restrict__ sumqi, float* __restrict__ sumko) {
    int b = blockIdx.x, sc = blockIdx.y;
    int w = threadIdx.x >> 6, lane = threadIdx.x & 63;
    float skL[8], sqL[8];
    #pragma unroll
    for (int j = 0; j < 8; ++j) {
        skL[j] = sumk[b * 512 + lane * 8 + j];
        sqL[j] = sumq[b * 512 + lane * 8 + j];
    }
    float aqi[8] = {}, ako[8] = {};
    int p0 = b * S_ + sc * 32 + w * 8;
    for (int it = 0; it < 8; ++it) {
        int p = p0 + it;
        size_t off = (size_t)p * 512 + lane * 8;
        u16x8 q8 = *(const u16x8*)(Qg + off);
        u16x8 k8 = *(const u16x8*)(Kg + off);
        float qf[8], kf[8];
        #pragma unroll
        for (int j = 0; j < 8; ++j) { qf[j] = bf2f(q8[j]); kf[j] = bf2f(k8[j]); }
        float di = 0.f, dox = 0.f;
        #pragma unroll
        for (int j = 0; j < 8; ++j) { di += qf[j] * skL[j]; dox += kf[j] * sqL[j]; }
        di  += __shfl_xor(di, 1);  di  += __shfl_xor(di, 2);  di  += __shfl_xor(di, 4);
        dox += __shfl_xor(dox, 1); dox += __shfl_xor(dox, 2); dox += __shfl_xor(dox, 4);
        if ((lane & 7) == 0) iv[(size_t)p * 8 + (lane >> 3)] = di;
        float ri = rcpf(di), ro = rcpf(dox);
        #pragma unroll
        for (int j = 0; j < 8; ++j) { aqi[j] += qf[j] * ri; ako[j] += kf[j] * ro; }
    }
    __shared__ float red[4][1024];
    #pragma unroll
    for (int j = 0; j < 8; ++j) {
        red[w][lane * 8 + j]       = aqi[j];
        red[w][512 + lane * 8 + j] = ako[j];
    }
    __syncthreads();
    int t = threadIdx.x;
    #pragma unroll
    for (int rr = 0; rr < 4; ++rr) {
        int slot = rr * 256 + t;
        float s = red[0][slot] + red[1][slot] + red[2][slot] + red[3][slot];
        float* dst = (slot < 512) ? &sumqi[b * 512 + slot] : &sumko[b * 512 + (slot - 512)];
        atomicAdd(dst, s);
    }
}

// ---------------- io2: i_hat,o_hat -> rowsc, wexp, sm partials  (grid (4,128) x 256) ----------------
__global__ __launch_bounds__(256) void io2_kernel(const u16* __restrict__ Qg, const u16* __restrict__ Kg,
                                                  const float* __restrict__ sumqi, const float* __restrict__ sumko,
                                                  const float* __restrict__ iv,
                                                  float* __restrict__ rowsc, float* __restrict__ wexp,
                                                  float* __restrict__ sm) {
    int b = blockIdx.x, sc = blockIdx.y;
    int w = threadIdx.x >> 6, lane = threadIdx.x & 63;
    float skoL[8], sqiL[8];
    #pragma unroll
    for (int j = 0; j < 8; ++j) {
        skoL[j] = sumko[b * 512 + lane * 8 + j];
        sqiL[j] = sumqi[b * 512 + lane * 8 + j];
    }
    float smacc = 0.f;
    int p0 = b * S_ + sc * 32 + w * 8;
    for (int it = 0; it < 8; ++it) {
        int p = p0 + it;
        size_t off = (size_t)p * 512 + lane * 8;
        u16x8 q8 = *(const u16x8*)(Qg + off);
        u16x8 k8 = *(const u16x8*)(Kg + off);
        float dih = 0.f, doh = 0.f;
        #pragma unroll
        for (int j = 0; j < 8; ++j) {
            dih += bf2f(q8[j]) * skoL[j];
            doh += bf2f(k8[j]) * sqiL[j];
        }
        dih += __shfl_xor(dih, 1); dih += __shfl_xor(dih, 2); dih += __shfl_xor(dih, 4);
        doh += __shfl_xor(doh, 1); doh += __shfl_xor(doh, 2); doh += __shfl_xor(doh, 4);
        if ((lane & 7) == 0) {
            int h = lane >> 3;
            float sig = 1.f / (1.f + __expf(-dih));
            rowsc[(size_t)p * 8 + h] = sig * rcpf(iv[(size_t)p * 8 + h]);
            float we = __expf(fminf(doh, 80.f));   // softmax w/o max-sub: o_hat ~ O(1)
            wexp[(size_t)p * 8 + h] = we;
            smacc += we;
        }
    }
    __shared__ float sr[4][8];
    if ((lane & 7) == 0) sr[w][lane >> 3] = smacc;
    __syncthreads();
    if (threadIdx.x < 8)
        atomicAdd(&sm[b * 8 + threadIdx.x],
                  sr[0][threadIdx.x] + sr[1][threadIdx.x] + sr[2][threadIdx.x] + sr[3][threadIdx.x]);
}

// ---------------- finalize: MFMA QK^T (2 pos/wave) + PV mix -> r bf16  (grid NPOS/8 x 256) ----------------
__global__ __launch_bounds__(256) void finalize_kernel(
        const u16* __restrict__ Qg, const u16* __restrict__ Kg, const u16* __restrict__ Vg,
        const float* __restrict__ rowsc, const float* __restrict__ wexp, const float* __restrict__ sm,
        u16* __restrict__ Rg) {
    __shared__ float Ml[4][2][8][9];
    __shared__ float vw[4][2][8][68];
    int w = threadIdx.x >> 6, lane = threadIdx.x & 63;
    int p0 = (blockIdx.x * 4 + w) * 2;
    int b = p0 >> 12;

    // QK^T via MFMA: A rows m = (p_l, h) from Q, B rows n = (p_l, h2) from K.
    {
        int pl = (lane >> 3) & 1, hh = lane & 7, quad = lane >> 4;
        const u16* qa = Qg + (size_t)(p0 + pl) * 512 + hh * 64 + quad * 8;
        const u16* ka = Kg + (size_t)(p0 + pl) * 512 + hh * 64 + quad * 8;
        bf16x8 a0 = __builtin_bit_cast(bf16x8, *(const u16x8*)qa);
        bf16x8 a1 = __builtin_bit_cast(bf16x8, *(const u16x8*)(qa + 32));
        bf16x8 b0 = __builtin_bit_cast(bf16x8, *(const u16x8*)ka);
        bf16x8 b1 = __builtin_bit_cast(bf16x8, *(const u16x8*)(ka + 32));
        f32x4 accm = {0.f, 0.f, 0.f, 0.f};
        accm = __builtin_amdgcn_mfma_f32_16x16x32_bf16(a0, b0, accm, 0, 0, 0);
        accm = __builtin_amdgcn_mfma_f32_16x16x32_bf16(a1, b1, accm, 0, 0, 0);
        // C: row=(lane>>4)*4+r, col=lane&15.  Keep diagonal p-quadrants.
        if (((lane >> 5) & 1) == ((lane >> 3) & 1)) {
            int plm = lane >> 5, hr = ((lane >> 4) & 1) * 4, h2 = lane & 7;
            #pragma unroll
            for (int r = 0; r < 4; ++r) Ml[w][plm][hr + r][h2] = accm[r];
        }
    }
    // vw = v * softmax-weight, fp32 in LDS
    {
        int hv = lane >> 3, e0 = (lane & 7) * 8;
        float invsm = rcpf(sm[b * 8 + hv]);
        #pragma unroll
        for (int pl = 0; pl < 2; ++pl) {
            u16x8 v8 = *(const u16x8*)(Vg + (size_t)(p0 + pl) * 512 + lane * 8);
            float wgt = wexp[(size_t)(p0 + pl) * 8 + hv] * invsm;
            f32x4 x0, x1;
            #pragma unroll
            for (int j = 0; j < 4; ++j) { x0[j] = bf2f(v8[j]) * wgt; x1[j] = bf2f(v8[4 + j]) * wgt; }
            *(f32x4*)&vw[w][pl][hv][e0]     = x0;
            *(f32x4*)&vw[w][pl][hv][e0 + 4] = x1;
        }
    }
    __syncthreads();   // order intra-wave cross-lane LDS deps safely
    // PV: lane covers (p_l = lane>>5, h = (lane&31)>>2, 16-elem e-chunk)
    {
        int pl = lane >> 5, idx = lane & 31, h = idx >> 2, eq = (idx & 3) * 16;
        float out[16] = {};
        #pragma unroll
        for (int h2 = 0; h2 < 8; ++h2) {
            float m = Ml[w][pl][h][h2];
            #pragma unroll
            for (int c = 0; c < 4; ++c) {
                f32x4 vv = *(const f32x4*)&vw[w][pl][h2][eq + c * 4];
                #pragma unroll
                for (int j = 0; j < 4; ++j) out[c * 4 + j] += m * vv[j];
            }
        }
        float rs = rowsc[(size_t)(p0 + pl) * 8 + h];
        u16x8 o0, o1;
        #pragma unroll
        for (int j = 0; j < 8; ++j) { o0[j] = f2bf(out[j] * rs); o1[j] = f2bf(out[8 + j] * rs); }
        u16* dst = Rg + (size_t)(p0 + pl) * 512 + h * 64 + eq;
        *(u16x8*)dst       = o0;
        *(u16x8*)(dst + 8) = o1;
    }
}

// ---------------- launch ----------------
extern "C" void kernel_launch(void* const* d_in, const int* in_sizes, int n_in,
                              void* d_out, int out_size, void* d_ws, size_t ws_size,
                              hipStream_t stream) {
    const float* x    = (const float*)d_in[0];
    const float* Wqkv = (const float*)d_in[1];
    const float* bqkv = (const float*)d_in[2];
    const float* Wout = (const float*)d_in[3];
    const float* bout = (const float*)d_in[4];
    float* out = (float*)d_out;
    char* ws = (char*)d_ws;

    constexpr size_t SZ_XBF  = (size_t)NPOS * E_ * 2;     // 16 MB (reused for r)
    constexpr size_t SZ_WQBF = (size_t)QKVC * E_ * 2;
    constexpr size_t SZ_WOBF = (size_t)E_ * E_ * 2;
    constexpr size_t SZ_QKVB = (size_t)NPOS * E_ * 2;     // 16 MB each of Q,K,V
    constexpr size_t SZ_SUM  = (size_t)B_ * 512 * 4;      // 8 KB each
    constexpr size_t SZ_V8   = (size_t)NPOS * 8 * 4;      // 512 KB each

    size_t off = 0;
    u16*   xbf   = (u16*)(ws + off);   off += SZ_XBF;
    u16*   wqbf  = (u16*)(ws + off);   off += SZ_WQBF;
    u16*   wobf  = (u16*)(ws + off);   off += SZ_WOBF;
    u16*   Qb    = (u16*)(ws + off);   off += SZ_QKVB;
    u16*   Kb    = (u16*)(ws + off);   off += SZ_QKVB;
    u16*   Vb    = (u16*)(ws + off);   off += SZ_QKVB;
    char*  zbase = ws + off;                       // contiguous zeroed region:
    float* sumq  = (float*)(ws + off); off += SZ_SUM;
    float* sumk  = (float*)(ws + off); off += SZ_SUM;
    float* sumqi = (float*)(ws + off); off += SZ_SUM;
    float* sumko = (float*)(ws + off); off += SZ_SUM;
    float* sm    = (float*)(ws + off); off += 256;
    size_t zlen  = (char*)(ws + off) - zbase;
    float* iv    = (float*)(ws + off); off += SZ_V8;
    float* rowsc = (float*)(ws + off); off += SZ_V8;
    float* wexp  = (float*)(ws + off); off += SZ_V8;
    u16*   rbf   = xbf;   // reuse after GEMM1

    hipMemsetAsync(zbase, 0, zlen, stream);

    cvt_all<<<(CVT_N1 + CVT_N2 + CVT_N3) / 256, 256, 0, stream>>>(
        (const float4*)x, (u16x4*)xbf,
        (const float4*)Wqkv, (u16x4*)wqbf,
        (const float4*)Wout, (u16x4*)wobf);

    gemm_qkv<<<dim3((QKVC / 128) * (NPOS / 128)), 256, 0, stream>>>(xbf, wqbf, bqkv, Qb, Kb, Vb, sumq, sumk, K_);

    fused_io<<<dim3(B_, 128), 256, 0, stream>>>(Qb, Kb, sumq, sumk, iv, sumqi, sumko);
    io2_kernel<<<dim3(B_, 128), 256, 0, stream>>>(Qb, Kb, sumqi, sumko, iv, rowsc, wexp, sm);
    finalize_kernel<<<NPOS / 8, 256, 0, stream>>>(Qb, Kb, Vb, rowsc, wexp, sm, rbf);

    gemm_out<<<dim3((E_ / 128) * (NPOS / 128)), 256, 0, stream>>>(rbf, wobf, bout, out, E_, K_);
}